// Round 6
// baseline (451.988 us; speedup 1.0000x reference)
//
#include <hip/hip_runtime.h>

// SimpleNet R6: MFMA f16 matmuls (R5 structure) + rational tanh on the FMA pipe.
// R5 was transcendental-issue-bound: v_exp/v_rcp ~16 issue-cyc per wave64 ->
// 224 trans x 16 = 3584 of 4050 busy cyc/iter. Replace with Eigen ptanh
// (deg13/deg6 rational), packed fp32 (v_pk_fma_f32), division via bit-trick
// rcp + 2 Newton (FMA pipe). Sigmoid = 0.5 + 0.5*tanh(y/2), 0.5 folded into w_out.
//
// MFMA layout (verified R5, absmax at bf16 floor): D[m=out_ch][n=pixel],
// mfma_f32_16x16x32_f16, 2 M-tiles, 2 N-tiles, K=32. Prep relabels A's k-cols by
// mu(k) so lane-group g's D regs are exactly next layer's B elems. No LDS.

#define HW_PIX (1024 * 1024)
#define NPIX   (4 * HW_PIX)
#define HID    25
#define DEPTH  6

typedef __fp16 h8 __attribute__((ext_vector_type(8)));
typedef __fp16 h2 __attribute__((ext_vector_type(2)));
typedef float f32x4 __attribute__((ext_vector_type(4)));
typedef float f2 __attribute__((ext_vector_type(2)));
typedef unsigned int u32x2 __attribute__((ext_vector_type(2)));

#define WS_WINP_BYTE 13312

__device__ __forceinline__ int mu_map(int k) {
    int g = k >> 3, j = k & 7;
    return (j < 4) ? (4 * g + j) : (16 + 4 * g + (j & 3));
}

__global__ __launch_bounds__(256) void prep_kernel(
    const float* __restrict__ w_in, const float* __restrict__ ws,
    const float* __restrict__ w_out, __fp16* __restrict__ wsA,
    float* __restrict__ winp)
{
    int tid = threadIdx.x;
    // hidden A-frags: 12 combos (layer l, tile t) x 64 lanes. RAW weights.
    for (int u = tid; u < 12 * 64; u += 256) {
        int q = u & 63, combo = u >> 6;
        int l = combo >> 1, t = combo & 1;
        int m = t * 16 + (q & 15);
        for (int j = 0; j < 8; ++j) {
            int k = (q >> 4) * 8 + j;
            int c = mu_map(k);
            float v = (m < HID && c < HID) ? ws[(l * HID + m) * HID + c] : 0.0f;
            wsA[u * 8 + j] = (__fp16)v;
        }
    }
    // output A-frag: w_out * 0.5 (sigmoid via tanh half-angle)
    if (tid < 64) {
        int q = tid, m = q & 15;
        for (int j = 0; j < 8; ++j) {
            int k = (q >> 4) * 8 + j;
            int c = mu_map(k);
            float v = (m < 3 && c < HID) ? w_out[m * HID + c] * 0.5f : 0.0f;
            wsA[(12 * 64 + q) * 8 + j] = (__fp16)v;
        }
    }
    // input weights, mu-ordered rows, raw
    if (tid < 32) {
        int k = tid, c = mu_map(k);
        for (int ci = 0; ci < 3; ++ci)
            winp[k * 3 + ci] = (c < HID) ? w_in[c * 3 + ci] : 0.0f;
    }
}

// packed reciprocal: bit-trick seed + 2 Newton iterations (d > 0 here)
__device__ __forceinline__ f2 rcp_pk(f2 d) {
    union { f2 f; u32x2 u; } a, b;
    a.f = d;
    b.u = (u32x2)0x7EF311C3u - a.u;
    f2 y = b.f;
    f2 two = 2.0f;
    f2 t = __builtin_elementwise_fma(-d, y, two);
    y = y * t;
    t = __builtin_elementwise_fma(-d, y, two);
    y = y * t;
    return y;
}

// Eigen ptanh: tanh(x) ~= x*P(x^2)/Q(x^2), clamp |x|<=7.90531 (rel err ~1e-4)
__device__ __forceinline__ f2 tanh_pk(f2 z) {
    const float C = 7.90531110763549805f;
    f2 x;
    x.x = __builtin_amdgcn_fmed3f(z.x, -C, C);
    x.y = __builtin_amdgcn_fmed3f(z.y, -C, C);
    f2 s = x * x;
    f2 p = (f2)(-2.76076847742355e-16f);
    p = __builtin_elementwise_fma(p, s, (f2)2.00018790482477e-13f);
    p = __builtin_elementwise_fma(p, s, (f2)(-8.60467152213735e-11f));
    p = __builtin_elementwise_fma(p, s, (f2)5.12229709037114e-08f);
    p = __builtin_elementwise_fma(p, s, (f2)1.48572235717979e-05f);
    p = __builtin_elementwise_fma(p, s, (f2)6.37261928875436e-04f);
    p = __builtin_elementwise_fma(p, s, (f2)4.89352455891786e-03f);
    p = p * x;
    f2 q = (f2)1.19825839466702e-06f;
    q = __builtin_elementwise_fma(q, s, (f2)1.18534705686654e-04f);
    q = __builtin_elementwise_fma(q, s, (f2)2.26843463243900e-03f);
    q = __builtin_elementwise_fma(q, s, (f2)4.89352518554385e-03f);
    return p * rcp_pk(q);
}

// 4 floats -> tanh -> packed fp16 pair-of-pairs (for B-fragment halves)
__device__ __forceinline__ void tanh4_to_h2(float a, float b, float c, float d,
                                            h2* o0, h2* o1) {
    f2 p0; p0.x = a; p0.y = b;
    f2 p1; p1.x = c; p1.y = d;
    f2 t0 = tanh_pk(p0);
    f2 t1 = tanh_pk(p1);
    *o0 = __builtin_amdgcn_cvt_pkrtz(t0.x, t0.y);
    *o1 = __builtin_amdgcn_cvt_pkrtz(t1.x, t1.y);
}

__global__ __launch_bounds__(256, 1) void simplenet_kernel(
    const float* __restrict__ x,
    const h8* __restrict__ wsA,
    const float* __restrict__ winp,
    float* __restrict__ out)
{
    const int lane = threadIdx.x & 63;
    const int wgid = blockIdx.x * 4 + (threadIdx.x >> 6);
    const int g = lane >> 4, col = lane & 15;

    h8 A[12];
#pragma unroll
    for (int i = 0; i < 12; ++i) A[i] = wsA[i * 64 + lane];
    h8 Aout = wsA[12 * 64 + lane];

    float wi[24];
    {
        const f32x4* wp4 = (const f32x4*)(winp + 8 * g * 3);
#pragma unroll
        for (int i = 0; i < 6; ++i) {
            f32x4 v = wp4[i];
            wi[i * 4 + 0] = v.x; wi[i * 4 + 1] = v.y; wi[i * 4 + 2] = v.z; wi[i * 4 + 3] = v.w;
        }
    }

    const int pbase = wgid * 512;
    const int b = pbase >> 20;
    const int hwb = pbase & (HW_PIX - 1);
    const float* xb = x + (size_t)b * 3 * HW_PIX;
    float* ob = out + (size_t)b * 3 * HW_PIX;

    for (int it = 0; it < 16; ++it) {
        const int hw0 = hwb + it * 32;

        // ---- input layer ----
        h8 B[2];
#pragma unroll
        for (int n = 0; n < 2; ++n) {
            const int hw = hw0 + n * 16 + col;
            float x0 = xb[0 * HW_PIX + hw];
            float x1 = xb[1 * HW_PIX + hw];
            float x2 = xb[2 * HW_PIX + hw];
            float th[8];
#pragma unroll
            for (int j = 0; j < 8; ++j) {
                float acc = wi[j * 3 + 0] * x0;
                acc = fmaf(wi[j * 3 + 1], x1, acc);
                acc = fmaf(wi[j * 3 + 2], x2, acc);
                th[j] = acc;
            }
            union { h8 v; h2 p[4]; } u;
            tanh4_to_h2(th[0], th[1], th[2], th[3], &u.p[0], &u.p[1]);
            tanh4_to_h2(th[4], th[5], th[6], th[7], &u.p[2], &u.p[3]);
            B[n] = u.v;
        }

        // ---- 6 hidden layers ----
#pragma unroll
        for (int l = 0; l < 6; ++l) {
#pragma unroll
            for (int n = 0; n < 2; ++n) {
                f32x4 zero = {0.0f, 0.0f, 0.0f, 0.0f};
                f32x4 d0 = __builtin_amdgcn_mfma_f32_16x16x32_f16(A[l * 2 + 0], B[n], zero, 0, 0, 0);
                f32x4 d1 = __builtin_amdgcn_mfma_f32_16x16x32_f16(A[l * 2 + 1], B[n], zero, 0, 0, 0);
                union { h8 v; h2 p[4]; } u;
                tanh4_to_h2(d0.x, d0.y, d0.z, d0.w, &u.p[0], &u.p[1]);
                tanh4_to_h2(d1.x, d1.y, d1.z, d1.w, &u.p[2], &u.p[3]);
                B[n] = u.v;
            }
        }

        // ---- output layer: sigmoid(y) = 0.5 + 0.5*tanh(y/2), w_out pre-halved ----
#pragma unroll
        for (int n = 0; n < 2; ++n) {
            f32x4 zero = {0.0f, 0.0f, 0.0f, 0.0f};
            f32x4 d = __builtin_amdgcn_mfma_f32_16x16x32_f16(Aout, B[n], zero, 0, 0, 0);
            if (g == 0) {
                f2 p0; p0.x = d.x; p0.y = d.y;
                f2 t0 = tanh_pk(p0);
                float t2 = tanh_pk((f2)d.z).x;
                const int hw = hw0 + n * 16 + col;
                ob[0 * HW_PIX + hw] = fmaf(0.5f, t0.x, 0.5f);
                ob[1 * HW_PIX + hw] = fmaf(0.5f, t0.y, 0.5f);
                ob[2 * HW_PIX + hw] = fmaf(0.5f, t2, 0.5f);
            }
        }
    }
}

extern "C" void kernel_launch(void* const* d_in, const int* in_sizes, int n_in,
                              void* d_out, int out_size, void* d_ws, size_t ws_size,
                              hipStream_t stream) {
    const float* x     = (const float*)d_in[0];
    const float* w_in  = (const float*)d_in[1];
    const float* ws    = (const float*)d_in[2];
    const float* w_out = (const float*)d_in[3];
    float* out         = (float*)d_out;

    __fp16* wsA = (__fp16*)d_ws;
    float* winp = (float*)((char*)d_ws + WS_WINP_BYTE);

    hipLaunchKernelGGL(prep_kernel, dim3(1), dim3(256), 0, stream,
                       w_in, ws, w_out, wsA, winp);

    hipLaunchKernelGGL(simplenet_kernel, dim3(2048), dim3(256), 0, stream,
                       x, (const h8*)d_ws, winp, out);
}